// Round 4
// baseline (4172.336 us; speedup 1.0000x reference)
//
#include <hip/hip_runtime.h>
#include <hip/hip_bf16.h>
#include <cstdint>
#include <cstddef>
#include <math.h>

// Problem constants
#define NE  8      // experts
#define NB  4      // batch
#define CAP 1024   // tokens/expert/batch
#define DM  2048   // d_model
#define DFF 8192   // d_ff
#define MPE (NB*CAP) // 4096 rows per expert

// Guide-verified fragment types (cdna_hip_programming.md §3): short-based bf16 frags.
typedef __attribute__((ext_vector_type(8))) short bf16x8;
typedef __attribute__((ext_vector_type(4))) float f32x4;

__device__ __forceinline__ unsigned short f2bf(float f) {
  union { float f; unsigned int u; } un; un.f = f;
  unsigned int u = un.u;
  u += 0x7fffu + ((u >> 16) & 1u);   // round-to-nearest-even
  return (unsigned short)(u >> 16);
}

__device__ __forceinline__ void gload16(const void* g, void* l) {
  __builtin_amdgcn_global_load_lds((const __attribute__((address_space(1))) void*)g,
                                   (__attribute__((address_space(3))) void*)l, 16, 0, 0);
}

// ---------------------------------------------------------------------------
// Prepass 1: x fp32 [NB][NE*CAP][DM] -> bf16 [E][NB*CAP][DM] (expert-major)
// one block per source row; 2048 elems = 512 float4; 256 thr x 2 iters
// ---------------------------------------------------------------------------
__global__ void cvt_permute_x(const float* __restrict__ x, unsigned short* __restrict__ xbf) {
  const int r  = blockIdx.x;          // 0..32767 global source row
  const int b  = r >> 13;             // / 8192
  const int tg = r & 8191;
  const int e  = tg >> 10;
  const int i  = tg & 1023;
  const size_t dstrow = (size_t)((e << 2) + b) * CAP + i;  // (e*NB+b)*CAP+i
  const float4* s = (const float4*)(x + (size_t)r * DM);
  ushort4* d = (ushort4*)(xbf + dstrow * DM);
  const int tid = threadIdx.x;
#pragma unroll
  for (int j = 0; j < 2; ++j) {
    const float4 v = s[tid + j * 256];
    ushort4 o;
    o.x = f2bf(v.x); o.y = f2bf(v.y); o.z = f2bf(v.z); o.w = f2bf(v.w);
    d[tid + j * 256] = o;
  }
}

// ---------------------------------------------------------------------------
// Prepass 2: transpose-convert  src fp32 [E][K][N] -> dst bf16 [E][N][K]
// 64x64 LDS tile, +1 pad. grid = (N/64, K/64, E), block 256.
// ---------------------------------------------------------------------------
__global__ void transpose_cvt(const float* __restrict__ src, unsigned short* __restrict__ dst,
                              int K, int N) {
  __shared__ float tile[64][65];
  const int e = blockIdx.z;
  const float* s = src + (size_t)e * K * N;
  unsigned short* d = dst + (size_t)e * K * N;
  const int n0 = blockIdx.x * 64, k0 = blockIdx.y * 64;
  const int tid = threadIdx.x;
  const int c4 = (tid & 15) * 4;
  const int r  = tid >> 4;
#pragma unroll
  for (int rr = 0; rr < 64; rr += 16) {
    const float4 v = *(const float4*)(s + (size_t)(k0 + r + rr) * N + n0 + c4);
    tile[r + rr][c4 + 0] = v.x;
    tile[r + rr][c4 + 1] = v.y;
    tile[r + rr][c4 + 2] = v.z;
    tile[r + rr][c4 + 3] = v.w;
  }
  __syncthreads();
  const int kq = (tid & 15) * 4;
#pragma unroll
  for (int nn = 0; nn < 64; nn += 16) {
    const int n = (tid >> 4) + nn;
    ushort4 o;
    o.x = f2bf(tile[kq + 0][n]);
    o.y = f2bf(tile[kq + 1][n]);
    o.z = f2bf(tile[kq + 2][n]);
    o.w = f2bf(tile[kq + 3][n]);
    *(ushort4*)(d + (size_t)(n0 + n) * K + k0 + kq) = o;
  }
}

// ---------------------------------------------------------------------------
// GEMM (m97 structure): C = epilogue(A[E][MPE][KD] @ Bt[E][ND][KD]^T + bias)
// 128x128 tile, BK=32, 4 waves (2x2), mfma_f32_16x16x32_bf16, 4x4 acc/wave.
// GELU=true : out = gelu(..)   -> bf16 h [E][MPE][DFF]
// GELU=false: out = ..         -> fp32 out, rows permuted back to [NB][NE*CAP][DM]
// ---------------------------------------------------------------------------
template<int KD, int ND, bool GELU>
__global__ __launch_bounds__(256, 2)
void gemm_bt(const unsigned short* __restrict__ A,
             const unsigned short* __restrict__ Bt,
             const float* __restrict__ bias,
             void* __restrict__ Cout) {
  __shared__ unsigned short As[128 * 32];
  __shared__ unsigned short Bs[128 * 32];
  const int e  = blockIdx.z;
  const int m0 = blockIdx.x * 128;
  const int n0 = blockIdx.y * 128;
  const int tid  = threadIdx.x;
  const int wave = tid >> 6, lane = tid & 63;
  const int wr = wave >> 1, wc = wave & 1;
  const int fr = lane & 15, fq = lane >> 4;

  const unsigned short* Ae = A  + (size_t)e * MPE * KD;
  const unsigned short* Be = Bt + (size_t)e * ND  * KD;

  // staging: tile is 128 rows x 64 bytes; 256 thr x 16B x 2 insts = 8192 B each
  const int b0  = wave * 1024 + lane * 16;
  const int b1i = b0 + 4096;
  const char* gA0 = (const char*)Ae + (size_t)(m0 + (b0  >> 6)) * (KD * 2) + (b0  & 63);
  const char* gA1 = (const char*)Ae + (size_t)(m0 + (b1i >> 6)) * (KD * 2) + (b1i & 63);
  const char* gB0 = (const char*)Be + (size_t)(n0 + (b0  >> 6)) * (KD * 2) + (b0  & 63);
  const char* gB1 = (const char*)Be + (size_t)(n0 + (b1i >> 6)) * (KD * 2) + (b1i & 63);
  char* lA0 = (char*)As + b0;  char* lA1 = (char*)As + b1i;
  char* lB0 = (char*)Bs + b0;  char* lB1 = (char*)Bs + b1i;

  f32x4 acc[4][4];
#pragma unroll
  for (int m = 0; m < 4; ++m)
#pragma unroll
    for (int n = 0; n < 4; ++n) acc[m][n] = (f32x4){0.f, 0.f, 0.f, 0.f};

#pragma unroll 1
  for (int kt = 0; kt < KD / 32; ++kt) {
    if (kt) __syncthreads();           // previous compute done before overwrite
    const size_t ko = (size_t)kt * 64; // 32 k * 2B
    gload16(gA0 + ko, lA0);
    gload16(gA1 + ko, lA1);
    gload16(gB0 + ko, lB0);
    gload16(gB1 + ko, lB1);
    __syncthreads();                   // compiler drains vmcnt before barrier

    bf16x8 a[4], b[4];
#pragma unroll
    for (int m = 0; m < 4; ++m)
      a[m] = *(const bf16x8*)((const char*)As + (wr * 64 + m * 16 + fr) * 64 + fq * 16);
#pragma unroll
    for (int n = 0; n < 4; ++n)
      b[n] = *(const bf16x8*)((const char*)Bs + (wc * 64 + n * 16 + fr) * 64 + fq * 16);
#pragma unroll
    for (int m = 0; m < 4; ++m)
#pragma unroll
      for (int n = 0; n < 4; ++n)
        acc[m][n] = __builtin_amdgcn_mfma_f32_16x16x32_bf16(a[m], b[n], acc[m][n], 0, 0, 0);
  }

  // Epilogue. C/D layout: col = lane&15, row = (lane>>4)*4 + reg (m89-verified).
  const float* be = bias + (size_t)e * ND;
  if constexpr (GELU) {
    unsigned short* H = (unsigned short*)Cout + (size_t)e * MPE * DFF;
#pragma unroll
    for (int m = 0; m < 4; ++m) {
#pragma unroll
      for (int n = 0; n < 4; ++n) {
        const int col = n0 + wc * 64 + n * 16 + fr;
        const float bv = be[col];
#pragma unroll
        for (int q = 0; q < 4; ++q) {
          const int row = m0 + wr * 64 + m * 16 + fq * 4 + q;
          const float v = acc[m][n][q] + bv;
          const float g = 0.5f * v * (1.0f + erff(v * 0.70710678118654752f));
          H[(size_t)row * DFF + col] = f2bf(g);
        }
      }
    }
  } else {
    float* O = (float*)Cout;
#pragma unroll
    for (int m = 0; m < 4; ++m) {
#pragma unroll
      for (int n = 0; n < 4; ++n) {
        const int col = n0 + wc * 64 + n * 16 + fr;
        const float bv = be[col];
#pragma unroll
        for (int q = 0; q < 4; ++q) {
          const int t = m0 + wr * 64 + m * 16 + fq * 4 + q;   // expert-token index
          const int grow = (t >> 10) * (NE * CAP) + e * CAP + (t & 1023);
          O[(size_t)grow * DM + col] = acc[m][n][q] + bv;
        }
      }
    }
  }
}

// ---------------------------------------------------------------------------
// Workspace layout (needs 1.125 GiB):
//  [0)                xbf  bf16  E*4096*2048   = 128 MiB
//  [128 MiB)          w1t  bf16  E*8192*2048   = 256 MiB  ([E][DFF][DM])
//  [384 MiB)          w2t  bf16  E*2048*8192   = 256 MiB  ([E][DM][DFF])
//  [640 MiB)          h    bf16  E*4096*8192   = 512 MiB
// ---------------------------------------------------------------------------
extern "C" void kernel_launch(void* const* d_in, const int* in_sizes, int n_in,
                              void* d_out, int out_size, void* d_ws, size_t ws_size,
                              hipStream_t stream) {
  (void)in_sizes; (void)n_in; (void)out_size; (void)ws_size;
  const float* x  = (const float*)d_in[0];
  const float* w1 = (const float*)d_in[1];
  const float* b1 = (const float*)d_in[2];
  const float* w2 = (const float*)d_in[3];
  const float* b2 = (const float*)d_in[4];
  float* out = (float*)d_out;

  char* ws = (char*)d_ws;
  unsigned short* xbf = (unsigned short*)(ws);
  unsigned short* w1t = (unsigned short*)(ws + 134217728ull);
  unsigned short* w2t = (unsigned short*)(ws + 134217728ull + 268435456ull);
  unsigned short* h   = (unsigned short*)(ws + 134217728ull + 2ull * 268435456ull);

  cvt_permute_x<<<dim3(NB * NE * CAP), 256, 0, stream>>>(x, xbf);
  transpose_cvt<<<dim3(DFF / 64, DM / 64, NE), 256, 0, stream>>>(w1, w1t, DM, DFF);
  transpose_cvt<<<dim3(DM / 64, DFF / 64, NE), 256, 0, stream>>>(w2, w2t, DFF, DM);

  gemm_bt<DM, DFF, true ><<<dim3(MPE / 128, DFF / 128, NE), 256, 0, stream>>>(xbf, w1t, b1, (void*)h);
  gemm_bt<DFF, DM, false><<<dim3(MPE / 128, DM / 128, NE), 256, 0, stream>>>(h, w2t, b2, (void*)out);
}